// Round 2
// 87.598 us; speedup vs baseline: 1.0116x; 1.0116x over previous
//
#include <hip/hip_runtime.h>
#include <math.h>

#define TPB 256           // k1 block size
#define SPT 2             // source points per thread in k1
#define TILE 128          // target points staged per LDS tile
#define TPB2 64           // k2 block size (1 wave)

// Kernel 1: partial min/max of pairwise squared distances, dot-product form.
// dist(s,t) = |s|^2 + (|t|^2 - 2 s.t). We track min/max of a = |t|^2 - 2 s.t
// and add |s|^2 in the epilogue (monotone shift commutes with min/max).
// Each thread owns SPT source points (i0, i0+TPB) so each broadcast LDS read
// of a target is amortized over 2*SPT distance updates (20 VALU ops / read).
// grid = (N/(TPB*SPT), S). part layout: [S][N] float4
// {min_start, max_start, min_end, max_end}.
__global__ __launch_bounds__(TPB) void k1_partial_minmax(
    const float* __restrict__ source,
    const float* __restrict__ target,
    const float* __restrict__ trans_m,
    float4* __restrict__ part,
    int* __restrict__ counter,
    int N, int M, int T, int S)
{
    // zero the k2 completion counter (k1 fully completes before k2 starts)
    if (blockIdx.x == 0 && blockIdx.y == 0 && threadIdx.x == 0) *counter = 0;

    const int chunk = M / S;
    const int s = blockIdx.y;
    const int i0 = blockIdx.x * (TPB * SPT) + threadIdx.x;

    __shared__ float4 tgt[TILE];

    float vsx[SPT], vsy[SPT], vsz[SPT];   // -2 * source coords
    float vex[SPT], vey[SPT], vez[SPT];   // -2 * denoised coords
    float ss[SPT], ee[SPT];
    float mins[SPT], maxs[SPT], mine[SPT], maxe[SPT];

    #pragma unroll
    for (int k = 0; k < SPT; ++k) {
        const int i = i0 + k * TPB;
        const float sx = source[(long)i * 3 + 0];
        const float sy = source[(long)i * 3 + 1];
        const float sz = source[(long)i * 3 + 2];
        const long teoff = (long)(T - 1) * N * 3 + (long)i * 3;
        const float ex = sx - trans_m[teoff + 0];
        const float ey = sy - trans_m[teoff + 1];
        const float ez = sz - trans_m[teoff + 2];
        ss[k] = fmaf(sx, sx, fmaf(sy, sy, sz * sz));
        ee[k] = fmaf(ex, ex, fmaf(ey, ey, ez * ez));
        vsx[k] = -2.0f * sx; vsy[k] = -2.0f * sy; vsz[k] = -2.0f * sz;
        vex[k] = -2.0f * ex; vey[k] = -2.0f * ey; vez[k] = -2.0f * ez;
        mins[k] = 3.402823e38f; maxs[k] = -3.402823e38f;
        mine[k] = 3.402823e38f; maxe[k] = -3.402823e38f;
    }

    const int t_begin = s * chunk;
    const int t_end   = t_begin + chunk;

    for (int t0 = t_begin; t0 < t_end; t0 += TILE) {
        __syncthreads();   // protect LDS before overwrite
        for (int j = threadIdx.x; j < TILE; j += TPB) {
            const float tx = target[(long)(t0 + j) * 3 + 0];
            const float ty = target[(long)(t0 + j) * 3 + 1];
            const float tz = target[(long)(t0 + j) * 3 + 2];
            const float q  = fmaf(tx, tx, fmaf(ty, ty, tz * tz));
            tgt[j] = make_float4(tx, ty, tz, q);
        }
        __syncthreads();

        #pragma unroll 8
        for (int j = 0; j < TILE; ++j) {
            const float4 t = tgt[j];
            #pragma unroll
            for (int k = 0; k < SPT; ++k) {
                float a = fmaf(vsx[k], t.x, t.w);
                a = fmaf(vsy[k], t.y, a);
                a = fmaf(vsz[k], t.z, a);
                mins[k] = fminf(mins[k], a);
                maxs[k] = fmaxf(maxs[k], a);
                float b = fmaf(vex[k], t.x, t.w);
                b = fmaf(vey[k], t.y, b);
                b = fmaf(vez[k], t.z, b);
                mine[k] = fminf(mine[k], b);
                maxe[k] = fmaxf(maxe[k], b);
            }
        }
    }

    #pragma unroll
    for (int k = 0; k < SPT; ++k) {
        const int i = i0 + k * TPB;
        part[(long)s * N + i] = make_float4(mins[k] + ss[k], maxs[k] + ss[k],
                                            mine[k] + ee[k], maxe[k] + ee[k]);
    }
}

// Kernel 2 (fused with final reduce): 128 blocks x 1 wave so the 8.4 MB
// partial array is pulled by 128 CUs instead of 32. Per-point loss + T-step
// scan, wave-sum, then last-done block sums blocksums[] with 64 parallel
// lanes (deterministic order within the shfl tree).
__global__ __launch_bounds__(TPB2) void k2_loss(
    const float4* __restrict__ part,
    const float* __restrict__ label,
    const float* __restrict__ path_m,
    const float* __restrict__ path_maxprob_m,
    float* __restrict__ blocksums,
    int* __restrict__ counter,
    float* __restrict__ out,
    int N, int S, int T)
{
    const int i = blockIdx.x * TPB2 + threadIdx.x;

    float mins = 3.402823e38f, maxs = -3.402823e38f;
    float mine = 3.402823e38f, maxe = -3.402823e38f;
    #pragma unroll 8
    for (int s = 0; s < S; ++s) {
        const float4 v = part[(long)s * N + i];
        mins = fminf(mins, v.x);
        maxs = fmaxf(maxs, v.y);
        mine = fminf(mine, v.z);
        maxe = fmaxf(maxe, v.w);
    }

    const float p = 0.002f, L0 = 0.4f, lam = 0.05f, gamma = 0.99f;
    const float loss_start = 0.99f * mins + 0.01f * maxs;
    const float loss_end   = 0.99f * mine + 0.01f * maxe;
    const float loss_dt    = loss_end - loss_start;
    const float d = fminf(loss_end / L0, 1.0f);
    const float l = expf(-label[i]);
    const float reward_end = -p * path_m[(long)(T - 1) * N + i]
                             - (d + lam * l) * loss_dt;

    // discounted return scan, t = T-1 .. 0:  R = g*R + lp*(r+0.02); L -= R
    float R = 0.0f, L = 0.0f;
    for (int t = T - 1; t >= 0; --t) {
        const float r  = (t == T - 1) ? reward_end
                                      : (-p * path_m[(long)t * N + i]);
        const float lp = logf(path_maxprob_m[(long)t * N + i]);
        R = gamma * R + lp * (r + 0.02f);
        L -= R;
    }
    float v = L / (float)T;   // per-point loss

    // single-wave reduction
    for (int off = 32; off > 0; off >>= 1) v += __shfl_down(v, off, 64);

    __shared__ bool amLast;
    if (threadIdx.x == 0) {
        blocksums[blockIdx.x] = v;
        __threadfence();                       // publish blocksum device-wide
        const int old = atomicAdd(counter, 1); // device-scope by default
        amLast = (old == (int)gridDim.x - 1);
    }
    __syncthreads();
    if (amLast) {
        __threadfence();                       // order reads after counter
        float t = 0.0f;
        for (int b = threadIdx.x; b < (int)gridDim.x; b += TPB2)
            t += ((volatile float*)blocksums)[b];
        for (int off = 32; off > 0; off >>= 1) t += __shfl_down(t, off, 64);
        if (threadIdx.x == 0) out[0] = t / (float)N;
    }
}

extern "C" void kernel_launch(void* const* d_in, const int* in_sizes, int n_in,
                              void* d_out, int out_size, void* d_ws, size_t ws_size,
                              hipStream_t stream) {
    const float* source = (const float*)d_in[0];
    const float* target = (const float*)d_in[1];
    const float* label  = (const float*)d_in[2];
    const float* trans  = (const float*)d_in[3];
    const float* path   = (const float*)d_in[4];
    const float* pmax   = (const float*)d_in[5];

    const int N = in_sizes[0] / 3;          // 8192
    const int M = in_sizes[1] / 3;          // 8192
    const int T = in_sizes[3] / (N * 3);    // 8
    const int nbx  = N / (TPB * SPT);       // 16
    const int nbx2 = N / TPB2;              // 128

    // choose target-dim split S (power of 2) so partials fit in d_ws
    // and chunk = M/S stays a multiple of TILE
    int S = 64;
    while (S > 1 && ((size_t)S * N * sizeof(float4)
                         + (size_t)(nbx2 + 1) * sizeof(float) > ws_size
                     || (M / S) < TILE))
        S >>= 1;

    float4* part     = (float4*)d_ws;                  // [S][N] float4
    float* blocksums = (float*)(part + (size_t)S * N); // [nbx2]
    int*   counter   = (int*)(blocksums + nbx2);       // [1]

    k1_partial_minmax<<<dim3(nbx, S), TPB, 0, stream>>>(
        source, target, trans, part, counter, N, M, T, S);
    k2_loss<<<nbx2, TPB2, 0, stream>>>(
        part, label, path, pmax, blocksums, counter, (float*)d_out, N, S, T);
}